// Round 8
// baseline (3203.586 us; speedup 1.0000x reference)
//
#include <hip/hip_runtime.h>

// Block-local LSTM (no inter-block communication, no barriers).
// 256 blocks x 512 threads (8 waves); block owns 16 batch rows.
// h-state bf16 in LDS, c-state fp32 in VGPRs, x staged in LDS.
// Weights: prepacked bf16 MFMA-B-fragment-major, streamed from per-XCD L2
// every step (1.5 MB/step live set, L2-resident once spill-free).

typedef __bf16 bf16x8 __attribute__((ext_vector_type(8)));
typedef float  f32x4  __attribute__((ext_vector_type(4)));

#define NMAT 12
#define MATSZ 262144   // 1024*256 elements per matrix
#define BIAS_OFF_BYTES 6291456  // 12*MATSZ*2

__device__ __host__ inline unsigned short f2bf_u(float f){
  union { float f; unsigned u; } v; v.f = f;
  unsigned u = v.u + 0x7fffu + ((v.u >> 16) & 1u);
  return (unsigned short)(u >> 16);
}
__device__ inline float bf2f(unsigned short h){ return __uint_as_float(((unsigned)h) << 16); }
__device__ inline float sigm(float x){ return 1.f / (1.f + __expf(-x)); }
__device__ inline float tanh_(float x){ return 2.f / (1.f + __expf(-2.f * x)) - 1.f; }

struct PrepArgs {
  const float* mats[NMAT];
  const float* ba[8];
  const float* bb[8];
  unsigned short* wp;
  float* bias;
};

// packed[((ntile*8 + kk)*64 + lane)*8 + j] = W[ntile*16 + (lane&15)][kk*32 + (lane>>4)*8 + j]
// (verified round 1)
__global__ void prep_kernel(PrepArgs a){
  unsigned i = blockIdx.x * 256u + threadIdx.x;
  if (i < (unsigned)NMAT * MATSZ) {
    unsigned mi = i >> 18;
    unsigned e  = i & (MATSZ - 1u);
    unsigned j  = e & 7u;
    unsigned l  = (e >> 3) & 63u;
    unsigned kk = (e >> 9) & 7u;
    unsigned nt = e >> 12;
    unsigned src = (nt * 16u + (l & 15u)) * 256u + kk * 32u + (l >> 4) * 8u + j;
    a.wp[i] = f2bf_u(a.mats[mi][src]);
  } else if (i < (unsigned)NMAT * MATSZ + 8192u) {
    unsigned e = i - (unsigned)NMAT * MATSZ;
    unsigned cell = e >> 10, n = e & 1023u;
    a.bias[e] = a.ba[cell][n] + a.bb[cell][n];
  }
}

// acc[ut][gt]: ntile = gt*16 + wave*2 + ut -> wave owns units [wave*32, wave*32+32),
// all 4 gates. Rows m = lg*4 + r (16 rows per block). kp-chunked to avoid spills.
__device__ inline void gemm_acc(f32x4 acc[2][4],
                                const unsigned short* __restrict__ Wp,
                                const unsigned short (*hb)[264],
                                int wave, int lane){
  const int lr = lane & 15, lg = lane >> 4;
  #pragma unroll
  for (int kp = 0; kp < 4; ++kp){
    bf16x8 A2[2];
    #pragma unroll
    for (int q = 0; q < 2; ++q)
      A2[q] = *reinterpret_cast<const bf16x8*>(&hb[lr][(kp * 2 + q) * 32 + lg * 8]);
    bf16x8 B2[2][4][2];
    #pragma unroll
    for (int ut = 0; ut < 2; ++ut){
      #pragma unroll
      for (int gt = 0; gt < 4; ++gt){
        const unsigned short* base = Wp + (size_t)(gt * 16 + wave * 2 + ut) * 4096
                                        + (size_t)lane * 8 + kp * 1024;
        B2[ut][gt][0] = *reinterpret_cast<const bf16x8*>(base);
        B2[ut][gt][1] = *reinterpret_cast<const bf16x8*>(base + 512);
      }
    }
    #pragma unroll
    for (int ut = 0; ut < 2; ++ut)
      #pragma unroll
      for (int gt = 0; gt < 4; ++gt){
        f32x4 c = __builtin_amdgcn_mfma_f32_16x16x32_bf16(A2[0], B2[ut][gt][0], acc[ut][gt], 0, 0, 0);
        acc[ut][gt] = __builtin_amdgcn_mfma_f32_16x16x32_bf16(A2[1], B2[ut][gt][1], c, 0, 0, 0);
      }
  }
}

__device__ inline void cell_upd(f32x4 acc[2][4], float cst[2][4],
                                unsigned short (*hb)[264], int wave, int lane){
  const int lr = lane & 15, lg = lane >> 4;
  #pragma unroll
  for (int ut = 0; ut < 2; ++ut){
    const int u = (wave * 2 + ut) * 16 + lr;
    #pragma unroll
    for (int r = 0; r < 4; ++r){
      const float gi = acc[ut][0][r], gf = acc[ut][1][r];
      const float gg = acc[ut][2][r], go = acc[ut][3][r];
      float c = sigm(gf) * cst[ut][r] + sigm(gi) * tanh_(gg);
      cst[ut][r] = c;
      hb[lg * 4 + r][u] = f2bf_u(sigm(go) * tanh_(c));
    }
  }
}

__device__ inline void init_bias(f32x4 acc[2][4], const float* __restrict__ b,
                                 int wave, int lr){
  #pragma unroll
  for (int ut = 0; ut < 2; ++ut){
    const int u = (wave * 2 + ut) * 16 + lr;
    #pragma unroll
    for (int gt = 0; gt < 4; ++gt){
      const float bb = b[gt * 256 + u];
      acc[ut][gt] = (f32x4){bb, bb, bb, bb};
    }
  }
}

struct MainArgs {
  const float* x;
  const float* encWih0;
  const float* decWih0;
  const float* headW;
  const float* headB;
  const float* confW;
  const float* confB;
  const unsigned short* wpack;
  const float* bias;
  float* out;
};

__global__ __launch_bounds__(512, 2) void lstm_main(MainArgs a){
  __shared__ float x_loc[16][200];
  __shared__ unsigned short hb0[16][264], hb1[16][264], hs0[16][264], hs1[16][264];
  __shared__ float pin[16][2];
  __shared__ float hw[512];
  __shared__ float cw[768];

  const int tid = threadIdx.x;
  const int wave = tid >> 6, lane = tid & 63;
  const int lr = lane & 15, lg = lane >> 4;
  const int m0 = blockIdx.x * 16;

  for (int i = tid; i < 16 * 200; i += 512)
    x_loc[i / 200][i % 200] = a.x[(size_t)(m0 + i / 200) * 200 + (i % 200)];
  for (int i = tid; i < 16 * 264; i += 512){
    (&hb0[0][0])[i] = 0; (&hb1[0][0])[i] = 0;
  }
  for (int i = tid; i < 768; i += 512) cw[i] = a.confW[i];
  float c0[2][4] = {}, c1[2][4] = {};
  __syncthreads();

  const unsigned short* Whh0p = a.wpack;
  const unsigned short* Wih1p = a.wpack + MATSZ;
  const unsigned short* Whh1p = a.wpack + 2 * MATSZ;
  const float* bias0 = a.bias;
  const float* bias1 = a.bias + 1024;

  // ---------------- encoder: 50 steps ----------------
  for (int t = 0; t < 50; ++t){
    f32x4 acc[2][4];
    init_bias(acc, bias0, wave, lr);
    // x @ Wih0^T (IN=4, fp32)
    {
      float4 w4[2][4];
      #pragma unroll
      for (int ut = 0; ut < 2; ++ut){
        const int u = (wave * 2 + ut) * 16 + lr;
        #pragma unroll
        for (int gt = 0; gt < 4; ++gt)
          w4[ut][gt] = *(const float4*)(a.encWih0 + (size_t)(gt * 256 + u) * 4);
      }
      #pragma unroll
      for (int r = 0; r < 4; ++r){
        const float4 xv = *(const float4*)(&x_loc[lg * 4 + r][t * 4]);
        #pragma unroll
        for (int ut = 0; ut < 2; ++ut)
          #pragma unroll
          for (int gt = 0; gt < 4; ++gt)
            acc[ut][gt][r] += xv.x * w4[ut][gt].x + xv.y * w4[ut][gt].y
                            + xv.z * w4[ut][gt].z + xv.w * w4[ut][gt].w;
      }
    }
    gemm_acc(acc, Whh0p, hb0, wave, lane);
    __syncthreads();
    cell_upd(acc, c0, hb0, wave, lane);
    __syncthreads();

    f32x4 acc2[2][4];
    init_bias(acc2, bias1, wave, lr);
    gemm_acc(acc2, Wih1p, hb0, wave, lane);   // Wih1 @ h0_new
    gemm_acc(acc2, Whh1p, hb1, wave, lane);   // Whh1 @ h1_old
    __syncthreads();
    cell_upd(acc2, c1, hb1, wave, lane);
    __syncthreads();
  }

  // ---------------- confidence head ----------------
  if (tid < 16){
    const int m = tid;
    float l3[3];
    #pragma unroll
    for (int j = 0; j < 3; ++j){
      float s = a.confB[j];
      for (int u = 0; u < 256; ++u) s += bf2f(hb1[m][u]) * cw[j * 256 + u];
      l3[j] = s;
    }
    const float mx = fmaxf(l3[0], fmaxf(l3[1], l3[2]));
    const float e0 = __expf(l3[0] - mx), e1 = __expf(l3[1] - mx), e2 = __expf(l3[2] - mx);
    const float inv = 1.f / (e0 + e1 + e2);
    a.out[147456 + (size_t)(m0 + m) * 3 + 0] = e0 * inv;
    a.out[147456 + (size_t)(m0 + m) * 3 + 1] = e1 * inv;
    a.out[147456 + (size_t)(m0 + m) * 3 + 2] = e2 * inv;
  }

  // save encoder-final state
  for (int i = tid; i < 16 * 264; i += 512){
    (&hs0[0][0])[i] = (&hb0[0][0])[i];
    (&hs1[0][0])[i] = (&hb1[0][0])[i];
  }
  float c0s[2][4], c1s[2][4];
  #pragma unroll
  for (int ut = 0; ut < 2; ++ut)
    #pragma unroll
    for (int r = 0; r < 4; ++r){ c0s[ut][r] = c0[ut][r]; c1s[ut][r] = c1[ut][r]; }
  __syncthreads();

  // ---------------- decoders ----------------
  for (int k = 0; k < 3; ++k){
    for (int i = tid; i < 16 * 264; i += 512){
      (&hb0[0][0])[i] = (&hs0[0][0])[i];
      (&hb1[0][0])[i] = (&hs1[0][0])[i];
    }
    #pragma unroll
    for (int ut = 0; ut < 2; ++ut)
      #pragma unroll
      for (int r = 0; r < 4; ++r){ c0[ut][r] = c0s[ut][r]; c1[ut][r] = c1s[ut][r]; }
    if (tid < 16){ pin[tid][0] = x_loc[tid][196]; pin[tid][1] = x_loc[tid][197]; }
    hw[tid] = a.headW[(size_t)k * 512 + tid];
    __syncthreads();

    const unsigned short* dWhh0p = a.wpack + (size_t)(3 + k) * MATSZ;
    const unsigned short* dWih1p = a.wpack + (size_t)(6 + k) * MATSZ;
    const unsigned short* dWhh1p = a.wpack + (size_t)(9 + k) * MATSZ;
    const float* db0 = a.bias + (size_t)(2 + k) * 1024;
    const float* db1 = a.bias + (size_t)(5 + k) * 1024;
    const float* dW2 = a.decWih0 + (size_t)k * 2048;

    for (int t = 0; t < 6; ++t){
      f32x4 acc[2][4];
      init_bias(acc, db0, wave, lr);
      {
        float2 w2[2][4];
        #pragma unroll
        for (int ut = 0; ut < 2; ++ut){
          const int u = (wave * 2 + ut) * 16 + lr;
          #pragma unroll
          for (int gt = 0; gt < 4; ++gt)
            w2[ut][gt] = *(const float2*)(dW2 + (size_t)(gt * 256 + u) * 2);
        }
        #pragma unroll
        for (int r = 0; r < 4; ++r){
          const float p0 = pin[lg * 4 + r][0], p1 = pin[lg * 4 + r][1];
          #pragma unroll
          for (int ut = 0; ut < 2; ++ut)
            #pragma unroll
            for (int gt = 0; gt < 4; ++gt)
              acc[ut][gt][r] += p0 * w2[ut][gt].x + p1 * w2[ut][gt].y;
        }
      }
      gemm_acc(acc, dWhh0p, hb0, wave, lane);
      __syncthreads();
      cell_upd(acc, c0, hb0, wave, lane);
      __syncthreads();

      f32x4 acc2[2][4];
      init_bias(acc2, db1, wave, lr);
      gemm_acc(acc2, dWih1p, hb0, wave, lane);
      gemm_acc(acc2, dWhh1p, hb1, wave, lane);
      __syncthreads();
      cell_upd(acc2, c1, hb1, wave, lane);
      __syncthreads();

      // pred head: 32 threads (16 rows x 2 dims)
      if (tid < 32){
        const int m = tid >> 1, d = tid & 1;
        float s = a.headB[k * 2 + d];
        for (int u = 0; u < 256; ++u) s += bf2f(hb1[m][u]) * hw[d * 256 + u];
        pin[m][d] = s;
        const size_t ob = (((size_t)(m0 + m) * 3 + k) * 6 + t) * 2 + d;
        a.out[ob] = s;
      }
      __syncthreads();
    }
  }
}

extern "C" void kernel_launch(void* const* d_in, const int* in_sizes, int n_in,
                              void* d_out, int out_size, void* d_ws, size_t ws_size,
                              hipStream_t stream){
  PrepArgs pa;
  pa.mats[0] = (const float*)d_in[2];   // enc_Whh0
  pa.mats[1] = (const float*)d_in[5];   // enc_Wih1
  pa.mats[2] = (const float*)d_in[6];   // enc_Whh1
  for (int k = 0; k < 3; ++k){
    pa.mats[3 + k] = (const float*)d_in[10] + (size_t)k * MATSZ;  // dec_Whh0[k]
    pa.mats[6 + k] = (const float*)d_in[13] + (size_t)k * MATSZ;  // dec_Wih1[k]
    pa.mats[9 + k] = (const float*)d_in[14] + (size_t)k * MATSZ;  // dec_Whh1[k]
  }
  pa.ba[0] = (const float*)d_in[3];  pa.bb[0] = (const float*)d_in[4];
  pa.ba[1] = (const float*)d_in[7];  pa.bb[1] = (const float*)d_in[8];
  for (int k = 0; k < 3; ++k){
    pa.ba[2 + k] = (const float*)d_in[11] + (size_t)k * 1024;
    pa.bb[2 + k] = (const float*)d_in[12] + (size_t)k * 1024;
    pa.ba[5 + k] = (const float*)d_in[15] + (size_t)k * 1024;
    pa.bb[5 + k] = (const float*)d_in[16] + (size_t)k * 1024;
  }
  pa.wp   = (unsigned short*)d_ws;
  pa.bias = (float*)((char*)d_ws + BIAS_OFF_BYTES);

  prep_kernel<<<12320, 256, 0, stream>>>(pa);

  MainArgs ma;
  ma.x       = (const float*)d_in[0];
  ma.encWih0 = (const float*)d_in[1];
  ma.decWih0 = (const float*)d_in[9];
  ma.headW   = (const float*)d_in[17];
  ma.headB   = (const float*)d_in[18];
  ma.confW   = (const float*)d_in[19];
  ma.confB   = (const float*)d_in[20];
  ma.wpack   = (const unsigned short*)d_ws;
  ma.bias    = (const float*)((char*)d_ws + BIAS_OFF_BYTES);
  ma.out     = (float*)d_out;

  lstm_main<<<256, 512, 0, stream>>>(ma);
}